// Round 5
// baseline (180.484 us; speedup 1.0000x reference)
//
// R14 = R13 resubmitted (previous two rounds failed on submission formatting, not code:
// the harness compiled my prose; this round the entire response is one cpp block).
//
// THEORY (baseline = R11, 173.8 us total):
//   (a) o_gemm -> 2-phase double-buffered LDS prefetch (T3-minimum): stage tile t+1
//       into buf^1 BEFORE computing tile t, one __syncthreads per K-step instead of
//       two with the stage serialized between them. 32 K-steps x ~500cy exposed
//       global-load latency becomes overlapped with MFMA+ds_read. LDS 24->48 KB.
//   (b) qkv_gemm256 -> bijective chunked XCD swizzle wgid=(bid%8)*24+bid/8 (192%8==0,
//       so ERRATA#11 hazard absent): the 16 blocks sharing a 512KB W panel co-locate
//       on one XCD L2. R10 capture showed FETCH 28.8MB vs ~14.7 ideal.
// PREDICTION: o_gemm -4..-6 us; qkv -0..-2 us (FETCH_SIZE -> ~18-20 MB if visible).
//   Total 173.8 -> ~166-169 us. absmax unchanged (0.005859375).
//   If neutral: o_gemm was already latency-hidden by inter-block TLP; next target is
//   attn (defer-max T13) or qkv grid shape (BN=192 -> 256 wg full-CU coverage).

#include <hip/hip_runtime.h>
#include <hip/hip_bf16.h>

// B=2, S=2048, D=1024, H=16, DK=64, BAND=100. Inputs f32 (auto-detect; bf16 fallback).

typedef __attribute__((ext_vector_type(8))) short short8;
typedef __attribute__((ext_vector_type(4))) float f32x4;

#define S_LEN 2048
#define NH 16
#define DK 64
#define BANDW 100

#define X_ELEMS   (2 * S_LEN * 1024)
#define W_ELEMS   (1024 * 1024)
#define QKV_ELEMS (2 * NH * S_LEN * DK)
#define AO_ELEMS  (2 * S_LEN * 1024)

__device__ __attribute__((aligned(256))) short g_X[X_ELEMS];
__device__ __attribute__((aligned(256))) short g_W[4 * W_ELEMS];   // Wq|Wk|Wv|Wo
__device__ __attribute__((aligned(256))) short g_b[4 * 1024];      // bq|bk|bv|bo
__device__ __attribute__((aligned(256))) short g_Q[QKV_ELEMS];     // pre-scaled by 1/8
__device__ __attribute__((aligned(256))) short g_K[QKV_ELEMS];
__device__ __attribute__((aligned(256))) short g_V[QKV_ELEMS];     // row-major [B,H,S,DK]
__device__ __attribute__((aligned(256))) short g_AO[AO_ELEMS];

__device__ __forceinline__ float bf2f(short u) {
    unsigned x = ((unsigned)(unsigned short)u) << 16;
    return __builtin_bit_cast(float, x);
}
__device__ __forceinline__ short f2bf(float f) {
    unsigned x = __builtin_bit_cast(unsigned, f);
    unsigned r = (x + 0x7fffu + ((x >> 16) & 1u)) >> 16;
    return (short)r;
}

#define GLOAD_LDS(gp, lp) \
    __builtin_amdgcn_global_load_lds( \
        (const __attribute__((address_space(1))) void*)(gp), \
        (__attribute__((address_space(3))) void*)(lp), 16, 0, 0)

// ---------------- Fused detect + convert (R9 form) ----------------
#define XC   (X_ELEMS / 8)
#define WC   (W_ELEMS / 8)
#define BC   (1024 / 8)
#define TOTC (XC + 4 * WC + 4 * BC)

__global__ __launch_bounds__(256) void convert_all(
    const void* __restrict__ x,
    const void* __restrict__ w0, const void* __restrict__ b0,
    const void* __restrict__ w1, const void* __restrict__ b1,
    const void* __restrict__ w2, const void* __restrict__ b2,
    const void* __restrict__ w3, const void* __restrict__ b3)
{
    __shared__ int cnt[256];
    {
        const unsigned* xw = (const unsigned*)x;
        int local = 0;
        #pragma unroll
        for (int i = 0; i < 4; i++) {
            unsigned wv = xw[threadIdx.x * 4 + i];
            unsigned e = (wv >> 7) & 0xFF;
            if (e >= 100 && e <= 140) local++;
        }
        cnt[threadIdx.x] = local;
    }
    __syncthreads();
    for (int s = 128; s > 0; s >>= 1) {
        if (threadIdx.x < s) cnt[threadIdx.x] += cnt[threadIdx.x + s];
        __syncthreads();
    }
    const int is_bf16 = (cnt[0] > 512);

    long i = (long)blockIdx.x * 256 + threadIdx.x;
    if (i >= TOTC) return;

    const void* src; short* dst; long off;
    if (i < XC)                { src = x;  dst = g_X;              off = i; }
    else if ((i -= XC) < WC)   { src = w0; dst = g_W + 0L*W_ELEMS; off = i; }
    else if ((i -= WC) < WC)   { src = w1; dst = g_W + 1L*W_ELEMS; off = i; }
    else if ((i -= WC) < WC)   { src = w2; dst = g_W + 2L*W_ELEMS; off = i; }
    else if ((i -= WC) < WC)   { src = w3; dst = g_W + 3L*W_ELEMS; off = i; }
    else if ((i -= WC) < BC)   { src = b0; dst = g_b + 0*1024;     off = i; }
    else if ((i -= BC) < BC)   { src = b1; dst = g_b + 1*1024;     off = i; }
    else if ((i -= BC) < BC)   { src = b2; dst = g_b + 2*1024;     off = i; }
    else                       { src = b3; dst = g_b + 3*1024;     off = i - BC; }

    if (is_bf16) {
        ((short8*)dst)[off] = ((const short8*)src)[off];
    } else {
        const float* s = (const float*)src + off * 8;
        short8 o;
        #pragma unroll
        for (int e = 0; e < 8; e++) o[e] = f2bf(s[e]);
        ((short8*)dst)[off] = o;
    }
}

// ---------------- Fused QKV GEMM: 256x256 tile, BK=64, 8-wave 8-phase ----------------
// M=4096 (B*S), N=3072 (q|k|v), K=1024. Out[m][n] = sum_k X[m][k]*W[n][k].
// LDS: 2 dbuf x {A,B} x 2 halves x [128][64] bf16 = 128 KiB.
// Swizzle (3-bit, G4-derived): LDS byte b of a region holds global element
// u = b ^ ((row(b)&7)<<4), row(b)=b>>7. Stage side: dest linear, source chunk
// (lane&7)^(lane>>3). Read side: chunk c^(fragrow&7). 8 lanes/slot x 8 slots ->
// conflict-free. Stage schedule: p0:A1^{T+1} p1:B1^{T+1} p2:B0^{T+2} p3:A0^{T+2};
// one vmcnt(4) per tile at p3-end (epilogue drain vmcnt(0) at T=14).
// XCD swizzle: wgid = (bid%8)*24 + bid/8 (bijective since 192%8==0).

#define LHALF 8192   // shorts per 16 KiB half-region

__global__ __launch_bounds__(512, 2) void qkv_gemm256()
{
    __shared__ __attribute__((aligned(16))) short L[8][LHALF]; // [buf*4 + mat*2 + half]

    const int t = threadIdx.x;
    const int lane = t & 63;
    const int w    = t >> 6;          // 0..7
    const int l15  = lane & 15;
    const int qg   = lane >> 4;       // 0..3
    const int wr   = w >> 2;          // 0..1  (M half owned by this wave)
    const int wc   = w & 3;           // 0..3  (N quarter)

    const int bid0 = blockIdx.x;                     // 0..191
    const int bid  = (bid0 & 7) * 24 + (bid0 >> 3);  // XCD-chunked, bijective
    const int mb  = (bid & 15) << 8;  // 16 M tiles
    const int nb  = (bid >> 4) << 8;  // 12 N tiles

    // staging geometry: lane's linear LDS bytes b = w*2048 + j*1024 + lane*16;
    // region row = w*16 + j*8 + (lane>>3); row&7 = lane>>3.
    // source chunk = (lane&7) ^ (lane>>3)  (16B chunks within the 128B row)
    const int srow = w * 16 + (lane >> 3);                        // + j*8
    const int scol = (((lane & 7) ^ (lane >> 3)) << 3);           // shorts
    const short* pA0 = g_X + (long)(mb       + srow) * 1024 + scol;
    const short* pA1 = g_X + (long)(mb + 128 + srow) * 1024 + scol;
    const short* pB0 = g_W + (long)(nb       + srow) * 1024 + scol;
    const short* pB1 = g_W + (long)(nb + 128 + srow) * 1024 + scol;
    const int ldst = w * 1024 + lane * 8;                         // shorts; +512 for j=1

#define STAGE(reg_, gp_, kt_) do {                         \
        short* lp_ = &L[(reg_)][ldst];                     \
        GLOAD_LDS((gp_) + (long)(kt_), lp_);               \
        GLOAD_LDS((gp_) + 8192 + (long)(kt_), lp_ + 512);  \
    } while (0)

#define BARRIER() asm volatile("s_barrier" ::: "memory")

    // read-side swizzle: fragment row = (..16-mult..) + l15 -> row&7 = l15&7
    const int axs    = (l15 & 7) << 3;            // XOR, in shorts (chunk ^ row&7)
    const int a_off0 = (qg << 3) ^ axs;           // kk = 0 (global chunks 0-3)
    const int a_off1 = (32 + (qg << 3)) ^ axs;    // kk = 1 (global chunks 4-7)
    const int brow   = (wc & 1) * 64;

    f32x4 acc[8][4] = {};

    // prologue: queue order B0^0, A0^0, A1^0, B1^0, B0^1, A0^1 (12 loads)
    STAGE(0*4 + 2 + 0, pB0, 0);
    STAGE(0*4 + 0 + 0, pA0, 0);
    STAGE(0*4 + 0 + 1, pA1, 0);
    STAGE(0*4 + 2 + 1, pB1, 0);
    STAGE(1*4 + 2 + 0, pB0, 64);
    STAGE(1*4 + 0 + 0, pA0, 64);
    asm volatile("s_waitcnt vmcnt(4)" ::: "memory");   // tile0's 4 halves landed
    BARRIER();

    for (int T = 0; T < 16; T++) {
        const int buf = T & 1;
        const short* Ah = L[buf*4 + wr];
        const short* Bh = L[buf*4 + 2 + (wc >> 1)];
        short8 afr[4][2], bfr[4][2];

        // ---------------- p0: read A mi0-3 + B ni0-1; stage A1^{T+1}; MFMA Q(lo,lo)
        #pragma unroll
        for (int mi = 0; mi < 4; mi++) {
            const int rb = (mi*16 + l15) * 64;
            afr[mi][0] = *(const short8*)(Ah + rb + a_off0);
            afr[mi][1] = *(const short8*)(Ah + rb + a_off1);
        }
        #pragma unroll
        for (int ni = 0; ni < 2; ni++) {
            const int rb = (brow + ni*16 + l15) * 64;
            bfr[ni][0] = *(const short8*)(Bh + rb + a_off0);
            bfr[ni][1] = *(const short8*)(Bh + rb + a_off1);
        }
        if (T + 1 < 16) STAGE(((T+1)&1)*4 + 1, pA1, (T+1)*64);
        BARRIER();
        __builtin_amdgcn_s_setprio(1);
        #pragma unroll
        for (int mi = 0; mi < 4; mi++)
            #pragma unroll
            for (int ni = 0; ni < 2; ni++) {
                acc[mi][ni] = __builtin_amdgcn_mfma_f32_16x16x32_bf16(afr[mi][0], bfr[ni][0], acc[mi][ni], 0, 0, 0);
                acc[mi][ni] = __builtin_amdgcn_mfma_f32_16x16x32_bf16(afr[mi][1], bfr[ni][1], acc[mi][ni], 0, 0, 0);
            }
        __builtin_amdgcn_s_setprio(0);
        BARRIER();

        // ---------------- p1: read B ni2-3; stage B1^{T+1}; MFMA Q(lo,hi)
        #pragma unroll
        for (int ni = 2; ni < 4; ni++) {
            const int rb = (brow + ni*16 + l15) * 64;
            bfr[ni][0] = *(const short8*)(Bh + rb + a_off0);
            bfr[ni][1] = *(const short8*)(Bh + rb + a_off1);
        }
        if (T + 1 < 16) STAGE(((T+1)&1)*4 + 2 + 1, pB1, (T+1)*64);
        BARRIER();
        __builtin_amdgcn_s_setprio(1);
        #pragma unroll
        for (int mi = 0; mi < 4; mi++)
            #pragma unroll
            for (int ni = 2; ni < 4; ni++) {
                acc[mi][ni] = __builtin_amdgcn_mfma_f32_16x16x32_bf16(afr[mi][0], bfr[ni][0], acc[mi][ni], 0, 0, 0);
                acc[mi][ni] = __builtin_amdgcn_mfma_f32_16x16x32_bf16(afr[mi][1], bfr[ni][1], acc[mi][ni], 0, 0, 0);
            }
        __builtin_amdgcn_s_setprio(0);
        BARRIER();

        // ---------------- p2: read A mi4-7; stage B0^{T+2}; MFMA Q(hi,hi)
        #pragma unroll
        for (int mi = 0; mi < 4; mi++) {
            const int rb = ((mi + 4)*16 + l15) * 64;
            afr[mi][0] = *(const short8*)(Ah + rb + a_off0);
            afr[mi][1] = *(const short8*)(Ah + rb + a_off1);
        }
        if (T + 2 < 16) STAGE((T&1)*4 + 2 + 0, pB0, (T+2)*64);
        BARRIER();
        __builtin_amdgcn_s_setprio(1);
        #pragma unroll
        for (int mi = 0; mi < 4; mi++)
            #pragma unroll
            for (int ni = 2; ni < 4; ni++) {
                acc[mi+4][ni] = __builtin_amdgcn_mfma_f32_16x16x32_bf16(afr[mi][0], bfr[ni][0], acc[mi+4][ni], 0, 0, 0);
                acc[mi+4][ni] = __builtin_amdgcn_mfma_f32_16x16x32_bf16(afr[mi][1], bfr[ni][1], acc[mi+4][ni], 0, 0, 0);
            }
        __builtin_amdgcn_s_setprio(0);
        BARRIER();

        // ---------------- p3: stage A0^{T+2}; MFMA Q(hi,lo); counted vmcnt; barrier
        if (T + 2 < 16) STAGE((T&1)*4 + 0, pA0, (T+2)*64);
        BARRIER();
        __builtin_amdgcn_s_setprio(1);
        #pragma unroll
        for (int mi = 0; mi < 4; mi++)
            #pragma unroll
            for (int ni = 0; ni < 2; ni++) {
                acc[mi+4][ni] = __builtin_amdgcn_mfma_f32_16x16x32_bf16(afr[mi][0], bfr[ni][0], acc[mi+4][ni], 0, 0, 0);
                acc[mi+4][ni] = __builtin_amdgcn_mfma_f32_16x16x32_bf16(afr[mi][1], bfr[ni][1], acc[mi+4][ni], 0, 0, 0);
            }
        __builtin_amdgcn_s_setprio(0);
        if (T <= 13)      asm volatile("s_waitcnt vmcnt(4)" ::: "memory");
        else if (T == 14) asm volatile("s_waitcnt vmcnt(0)" ::: "memory");
        BARRIER();
    }

    // ------- epilogue: bias (+ Q scale); ni innermost so each 128B line completes -------
    const int nbase = nb + wc * 64;       // 64-aligned, single z and single h per wave
    const int z = nbase >> 10;
    short* __restrict__ Out = (z == 0) ? g_Q : ((z == 1) ? g_K : g_V);
    const float scale = (z == 0) ? 0.125f : 1.0f;
    const int c0 = nbase & 1023;
    const int h = c0 >> 6;                // d = ni*16 + l15 (c0&63 == 0)
    float bv4[4];
    #pragma unroll
    for (int ni = 0; ni < 4; ni++) bv4[ni] = bf2f(g_b[z * 1024 + c0 + ni * 16 + l15]);
    const int rg = qg * 4;
    #pragma unroll
    for (int mi = 0; mi < 8; mi++) {
        #pragma unroll
        for (int r = 0; r < 4; r++) {
            const int row = mb + wr * 128 + mi * 16 + rg + r;
            const int bI = row >> 11, s = row & 2047;
            short* op = Out + (((long)(bI * NH + h) * S_LEN) + s) * DK;
            #pragma unroll
            for (int ni = 0; ni < 4; ni++)
                op[ni * 16 + l15] = f2bf((acc[mi][ni][r] + bv4[ni]) * scale);
        }
    }
#undef STAGE
#undef BARRIER
}

// ------ Out-proj R14: 128x64 tiles, BK=32, dbuf prefetch, ONE barrier per K-step ------
// Stage tile t+1 into buf^1 while computing tile t; __syncthreads (implicit
// vmcnt0+lgkm0 drain) once per step. LDS 48 KB.
__global__ __launch_bounds__(256) void o_gemm(float* __restrict__ Out)
{
    __shared__ __attribute__((aligned(16))) short As[2][128 * 32];
    __shared__ __attribute__((aligned(16))) short Bs[2][64 * 32];

    const short* __restrict__ A = g_AO;
    const short* __restrict__ W = g_W + 3L * W_ELEMS;

    const int t = threadIdx.x;
    const int lane = t & 63;
    const int wid  = t >> 6;
    const int wm = wid & 1, wn = wid >> 1;
    const int l15 = lane & 15;
    const int q8  = (lane >> 4) * 8;
    const int mb = blockIdx.x * 128;
    const int nb = blockIdx.y * 64;

    const long ga0 = (long)(mb + (t >> 2)) * 1024 + (t & 3) * 8;
    const long ga1 = (long)(mb + 64 + (t >> 2)) * 1024 + (t & 3) * 8;
    const long gb0 = (long)(nb + (t >> 2)) * 1024 + (t & 3) * 8;

    f32x4 acc[4][2] = {};

    // prologue: tile 0 -> buf 0
    GLOAD_LDS(A + ga0, As[0] + t * 8);
    GLOAD_LDS(A + ga1, As[0] + 2048 + t * 8);
    GLOAD_LDS(W + gb0, Bs[0] + t * 8);
    __syncthreads();   // implicit vmcnt(0) drain

    for (int k0 = 0; k0 < 1024; k0 += 32) {
        const int cur = (k0 >> 5) & 1;
        if (k0 + 32 < 1024) {
            GLOAD_LDS(A + ga0 + k0 + 32, As[cur ^ 1] + t * 8);
            GLOAD_LDS(A + ga1 + k0 + 32, As[cur ^ 1] + 2048 + t * 8);
            GLOAD_LDS(W + gb0 + k0 + 32, Bs[cur ^ 1] + t * 8);
        }
        short8 a[4], b[2];
        #pragma unroll
        for (int mt = 0; mt < 4; mt++) a[mt] = *(const short8*)(As[cur] + (wm * 64 + mt * 16 + l15) * 32 + q8);
        #pragma unroll
        for (int nt = 0; nt < 2; nt++) b[nt] = *(const short8*)(Bs[cur] + (wn * 32 + nt * 16 + l15) * 32 + q8);
        #pragma unroll
        for (int mt = 0; mt < 4; mt++)
            #pragma unroll
            for (int nt = 0; nt < 2; nt++)
                acc[mt][nt] = __builtin_amdgcn_mfma_f32_16x16x32_bf16(a[mt], b[nt], acc[mt][nt], 0, 0, 0);
        __syncthreads();   // next buf landed (vmcnt0) + all reads of cur done
    }

    const int rg = (lane >> 4) * 4;
    #pragma unroll
    for (int nt = 0; nt < 2; nt++) {
        const int col = nb + wn * 32 + nt * 16 + l15;
        const float bv_ = bf2f(g_b[3 * 1024 + col]);
        #pragma unroll
        for (int mt = 0; mt < 4; mt++) {
            #pragma unroll
            for (int r = 0; r < 4; r++) {
                const int row = mb + wm * 64 + mt * 16 + rg + r;
                Out[(long)row * 1024 + col] = acc[mt][nt][r] + bv_;
            }
        }
    }
}

// ------- Banded attention: 64 q/block, online softmax, K prefetch, XCD swizzle ------
// bid = qt*32 + head  =>  bid%8 == head%8: one head's q-tiles share an XCD L2.
#define VT_PAD 328   // 656 B = 164 dw; 164%32=4 -> 4-bank row skew (2-way, free)

__global__ __launch_bounds__(256) void attn_kernel()
{
    __shared__ __attribute__((aligned(16))) short Vt[64][VT_PAD];   // [dim][key-kb0]
    __shared__ __attribute__((aligned(16))) short Pl[4][16][72];    // per-wave P [row][key]

    const int bid  = blockIdx.x;
    const int head = bid & 31;          // b*16+h
    const int qt   = bid >> 5;          // 0..31
    const int h = head & 15, b = head >> 4;
    const int qbase = qt * 64;

    const int lane = threadIdx.x & 63;
    const int w    = threadIdx.x >> 6;
    const int l15  = lane & 15;
    const int qg   = lane >> 4;
    const int q8   = qg * 8;

    const long hoff = (long)(b * NH + h) * S_LEN * DK;
    const short* __restrict__ Qh = g_Q + hoff;
    const short* __restrict__ Kh = g_K + hoff;
    const short* __restrict__ Vh = g_V + hoff;

    const int lo  = qbase - (BANDW - 1);
    const int kc0 = (lo < 0 ? 0 : lo) >> 6;
    int hi = qbase + 64 + (BANDW - 1);
    if (hi > S_LEN) hi = S_LEN;
    const int kc1 = (hi + 63) >> 6;
    const int kb0 = kc0 * 64;
    const int n_keys = (kc1 - kc0) * 64;   // <= 320

    // Q fragments (already pre-scaled by 1/8 at projection)
    const short* qp = Qh + (long)(qbase + w * 16 + l15) * DK + q8;
    const short8 aq0 = *(const short8*)(qp);
    const short8 aq1 = *(const short8*)(qp + 32);

    // ---- stage whole-band V^T, two keys per thread, paired 4B writes ----
    const int npairs = n_keys >> 1;
    for (int u = threadIdx.x; u < npairs; u += 256) {
        const short* vp0 = Vh + (long)(kb0 + 2 * u) * DK;
        #pragma unroll
        for (int tq = 0; tq < 8; tq++) {
            const short8 v0 = *(const short8*)(vp0 + tq * 8);
            const short8 v1 = *(const short8*)(vp0 + DK + tq * 8);
            #pragma unroll
            for (int e = 0; e < 8; e++) {
                const int pk = (int)(unsigned short)v0[e] | ((int)(unsigned short)v1[e] << 16);
                *(int*)&Vt[tq * 8 + e][2 * u] = pk;
            }
        }
    }
    __syncthreads();   // only block barrier

    // ---- prefetch first chunk's K fragments ----
    short8 nk0[4], nk1[4];
    #pragma unroll
    for (int nt = 0; nt < 4; nt++) {
        const short* kp = Kh + (long)(kb0 + nt * 16 + l15) * DK + q8;
        nk0[nt] = *(const short8*)(kp);
        nk1[nt] = *(const short8*)(kp + 32);
    }

    f32x4 o[4] = {};
    float m_r[4], l_r[4];
    #pragma unroll
    for (int r = 0; r < 4; r++) { m_r[r] = -1e30f; l_r[r] = 0.f; }

    for (int kc = kc0; kc < kc1; kc++) {
        const int kb = kc * 64;
        const int kloc = kb - kb0;

        // consume prefetched K; immediately issue next chunk's loads
        short8 bk0[4], bk1[4];
        #pragma unroll
        for (int nt = 0; nt < 4; nt++) { bk0[nt] = nk0[nt]; bk1[nt] = nk1[nt]; }
        if (kc + 1 < kc1) {
            const int kbn = kb + 64;
            #pragma unroll
            for (int nt = 0; nt < 4; nt++) {
                const short* kp = Kh + (long)(kbn + nt * 16 + l15) * DK + q8;
                nk0[nt] = *(const short8*)(kp);
                nk1[nt] = *(const short8*)(kp + 32);
            }
        }

        // S-tile = (Q/8) K^T
        f32x4 sc[4];
        #pragma unroll
        for (int nt = 0; nt < 4; nt++) {
            f32x4 z = {};
            z = __builtin_amdgcn_mfma_f32_16x16x32_bf16(aq0, bk0[nt], z, 0, 0, 0);
            z = __builtin_amdgcn_mfma_f32_16x16x32_bf16(aq1, bk1[nt], z, 0, 0, 0);
            sc[nt] = z;
        }

        float pv[4][4];
        float mx[4] = {-1e30f, -1e30f, -1e30f, -1e30f};
        if (kb == qbase) {
            // diagonal chunk: fully inside band, skip mask arithmetic
            #pragma unroll
            for (int nt = 0; nt < 4; nt++)
                #pragma unroll
                for (int r = 0; r < 4; r++) {
                    pv[nt][r] = sc[nt][r];
                    mx[r] = fmaxf(mx[r], sc[nt][r]);
                }
        } else {
            #pragma unroll
            for (int nt = 0; nt < 4; nt++) {
                const int kg = kb + nt * 16 + l15;
                #pragma unroll
                for (int r = 0; r < 4; r++) {
                    const int qI = qbase + w * 16 + qg * 4 + r;
                    int dlt = qI - kg; if (dlt < 0) dlt = -dlt;
                    const float v = (dlt < BANDW) ? sc[nt][r] : -1e30f;
                    pv[nt][r] = v;
                    mx[r] = fmaxf(mx[r], v);
                }
            }
        }
        #pragma unroll
        for (int mk = 1; mk < 16; mk <<= 1)
            #pragma unroll
            for (int r = 0; r < 4; r++) mx[r] = fmaxf(mx[r], __shfl_xor(mx[r], mk, 64));

        float alpha[4], lnew[4];
        #pragma unroll
        for (int r = 0; r < 4; r++) {
            const float mn = fmaxf(m_r[r], mx[r]);
            alpha[r] = __builtin_exp2f((m_r[r] - mn) * 1.44269504f);
            m_r[r] = mn;
            lnew[r] = 0.f;
        }
        #pragma unroll
        for (int nt = 0; nt < 4; nt++)
            #pragma unroll
            for (int r = 0; r < 4; r++) {
                const float p = (pv[nt][r] > -0.5e30f)
                    ? __builtin_exp2f((pv[nt][r] - m_r[r]) * 1.44269504f) : 0.f;
                pv[nt][r] = p;
                lnew[r] += p;
            }
        #pragma unroll
        for (int mk = 1; mk < 16; mk <<= 1)
            #pragma unroll
            for (int r = 0; r < 4; r++) lnew[r] += __shfl_xor(lnew[r], mk, 64);
        #pragma unroll
        for (int r = 0; r < 4; r++) l_r[r] = l_r[r] * alpha[r] + lnew[r];
        #pragma unroll
        for (int nt2 = 0; nt2 < 4; nt2++)
            #pragma unroll
            for (int r = 0; r < 4; r++) o[nt2][r] *= alpha[r];

        // P (C layout) -> per-wave LDS -> A layout (lgkm wait only)
        #pragma unroll
        for (int nt = 0; nt < 4; nt++)
            #pragma unroll
            for (int r = 0; r < 4; r++)
                Pl[w][qg * 4 + r][nt * 16 + l15] = f2bf(pv[nt][r]);
        asm volatile("s_waitcnt lgkmcnt(0)" ::: "memory");
        const short8 ap0 = *(const short8*)(&Pl[w][l15][q8]);
        const short8 ap1 = *(const short8*)(&Pl[w][l15][32 + q8]);

        #pragma unroll
        for (int nt2 = 0; nt2 < 4; nt2++) {
            const short* vrow = &Vt[nt2 * 16 + l15][kloc];
            const short8 bv0 = *(const short8*)(vrow + q8);
            const short8 bv1 = *(const short8*)(vrow + 32 + q8);
            o[nt2] = __builtin_amdgcn_mfma_f32_16x16x32_bf16(ap0, bv0, o[nt2], 0, 0, 0);
            o[nt2] = __builtin_amdgcn_mfma_f32_16x16x32_bf16(ap1, bv1, o[nt2], 0, 0, 0);
        }
    }

    #pragma unroll
    for (int nt2 = 0; nt2 < 4; nt2++)
        #pragma unroll
        for (int r = 0; r < 4; r++) {
            const int qI = qbase + w * 16 + qg * 4 + r;
            const int d = nt2 * 16 + l15;
            g_AO[((long)b * S_LEN + qI) * 1024 + h * DK + d] = f2bf(o[nt2][r] / l_r[r]);
        }
}

extern "C" void kernel_launch(void* const* d_in, const int* in_sizes, int n_in,
                              void* d_out, int out_size, void* d_ws, size_t ws_size,
                              hipStream_t stream) {
    float* out = (float*)d_out;

    convert_all<<<(TOTC + 255) / 256, 256, 0, stream>>>(
        d_in[0], d_in[1], d_in[2], d_in[3], d_in[4], d_in[5], d_in[6], d_in[7], d_in[8]);
    qkv_gemm256<<<dim3(192), 512, 0, stream>>>();
    attn_kernel<<<dim3(2 * NH * (S_LEN / 64)), 256, 0, stream>>>();
    o_gemm<<<dim3(32, 16), 256, 0, stream>>>(out);
}

// Round 6
// 176.559 us; speedup vs baseline: 1.0222x; 1.0222x over previous
//
#include <hip/hip_runtime.h>
#include <hip/hip_bf16.h>

// B=2, S=2048, D=1024, H=16, DK=64, BAND=100. Inputs f32 (auto-detect; bf16 fallback).
// Output f32. R15: (a) revert R14's XCD chunk swizzle (linear bid had better A-panel
// L2 locality: each XCD sees only 2 A-panels); (b) keep o_gemm dbuf; (c) qkv retiled
// 256x192, grid 16x16=256 blocks = exactly 1/CU (was 192/256 CUs = 25% idle).
// B staged as 3x64-row regions (1 gload_lds per thread each); LDS 112KB; vmcnt(2).

typedef __attribute__((ext_vector_type(8))) short short8;
typedef __attribute__((ext_vector_type(4))) float f32x4;

#define S_LEN 2048
#define NH 16
#define DK 64
#define BANDW 100

#define X_ELEMS   (2 * S_LEN * 1024)
#define W_ELEMS   (1024 * 1024)
#define QKV_ELEMS (2 * NH * S_LEN * DK)
#define AO_ELEMS  (2 * S_LEN * 1024)

__device__ __attribute__((aligned(256))) short g_X[X_ELEMS];
__device__ __attribute__((aligned(256))) short g_W[4 * W_ELEMS];   // Wq|Wk|Wv|Wo
__device__ __attribute__((aligned(256))) short g_b[4 * 1024];      // bq|bk|bv|bo
__device__ __attribute__((aligned(256))) short g_Q[QKV_ELEMS];     // pre-scaled by 1/8
__device__ __attribute__((aligned(256))) short g_K[QKV_ELEMS];
__device__ __attribute__((aligned(256))) short g_V[QKV_ELEMS];     // row-major [B,H,S,DK]
__device__ __attribute__((aligned(256))) short g_AO[AO_ELEMS];

__device__ __forceinline__ float bf2f(short u) {
    unsigned x = ((unsigned)(unsigned short)u) << 16;
    return __builtin_bit_cast(float, x);
}
__device__ __forceinline__ short f2bf(float f) {
    unsigned x = __builtin_bit_cast(unsigned, f);
    unsigned r = (x + 0x7fffu + ((x >> 16) & 1u)) >> 16;
    return (short)r;
}

#define GLOAD_LDS(gp, lp) \
    __builtin_amdgcn_global_load_lds( \
        (const __attribute__((address_space(1))) void*)(gp), \
        (__attribute__((address_space(3))) void*)(lp), 16, 0, 0)

// ---------------- Fused detect + convert (R9 form) ----------------
#define XC   (X_ELEMS / 8)
#define WC   (W_ELEMS / 8)
#define BC   (1024 / 8)
#define TOTC (XC + 4 * WC + 4 * BC)

__global__ __launch_bounds__(256) void convert_all(
    const void* __restrict__ x,
    const void* __restrict__ w0, const void* __restrict__ b0,
    const void* __restrict__ w1, const void* __restrict__ b1,
    const void* __restrict__ w2, const void* __restrict__ b2,
    const void* __restrict__ w3, const void* __restrict__ b3)
{
    __shared__ int cnt[256];
    {
        const unsigned* xw = (const unsigned*)x;
        int local = 0;
        #pragma unroll
        for (int i = 0; i < 4; i++) {
            unsigned wv = xw[threadIdx.x * 4 + i];
            unsigned e = (wv >> 7) & 0xFF;
            if (e >= 100 && e <= 140) local++;
        }
        cnt[threadIdx.x] = local;
    }
    __syncthreads();
    for (int s = 128; s > 0; s >>= 1) {
        if (threadIdx.x < s) cnt[threadIdx.x] += cnt[threadIdx.x + s];
        __syncthreads();
    }
    const int is_bf16 = (cnt[0] > 512);

    long i = (long)blockIdx.x * 256 + threadIdx.x;
    if (i >= TOTC) return;

    const void* src; short* dst; long off;
    if (i < XC)                { src = x;  dst = g_X;              off = i; }
    else if ((i -= XC) < WC)   { src = w0; dst = g_W + 0L*W_ELEMS; off = i; }
    else if ((i -= WC) < WC)   { src = w1; dst = g_W + 1L*W_ELEMS; off = i; }
    else if ((i -= WC) < WC)   { src = w2; dst = g_W + 2L*W_ELEMS; off = i; }
    else if ((i -= WC) < WC)   { src = w3; dst = g_W + 3L*W_ELEMS; off = i; }
    else if ((i -= WC) < BC)   { src = b0; dst = g_b + 0*1024;     off = i; }
    else if ((i -= BC) < BC)   { src = b1; dst = g_b + 1*1024;     off = i; }
    else if ((i -= BC) < BC)   { src = b2; dst = g_b + 2*1024;     off = i; }
    else                       { src = b3; dst = g_b + 3*1024;     off = i - BC; }

    if (is_bf16) {
        ((short8*)dst)[off] = ((const short8*)src)[off];
    } else {
        const float* s = (const float*)src + off * 8;
        short8 o;
        #pragma unroll
        for (int e = 0; e < 8; e++) o[e] = f2bf(s[e]);
        ((short8*)dst)[off] = o;
    }
}

// ---------------- Fused QKV GEMM: 256x192 tile, BK=64, 8-wave 4-phase ----------------
// M=4096, N=3072 (q|k|v), K=1024. Grid 16x16 = 256 blocks = 1/CU, all CUs busy.
// LDS/buffer: A0(16K) A1(16K) B0(8K) B1(8K) B2(8K) = 56KB; x2 dbuf = 112KB.
// Per wave (2M x 4N): 128 x 48 output, acc[8][3].
// Swizzle (R11-proven): LDS byte b of a region holds global elem u = b ^ ((row&7)<<4);
// stage side: linear dest, source chunk (lane&7)^(row&7); read side: chunk ^ (l15&7).
// Stage schedule: p0: A1^{T+1}(2); p1: B012^{T+1}(3); p2: none; p3: A0^{T+2}(2)
//   (A0^{T+2} overwrites current buffer's A0 region -> must be after p2-end barrier,
//    which follows the last A0 reads at p2. Read-safety mirrors R11's proof.)
// End-of-tile: vmcnt(2) keeps A0^{T+2} in flight (T<=13); T==14 drains vmcnt(0).

#define QKV_NT 16          // K tiles (1024/64)
#define BUFS  28672        // shorts per buffer (56KB)
#define RA0   0
#define RA1   8192
#define RB0   16384
#define RB1   20480
#define RB2   24576

__global__ __launch_bounds__(512, 2) void qkv_gemm256()
{
    __shared__ __attribute__((aligned(16))) short L[2][BUFS];

    const int t = threadIdx.x;
    const int lane = t & 63;
    const int w    = t >> 6;          // 0..7
    const int l15  = lane & 15;
    const int qg   = lane >> 4;       // 0..3
    const int wr   = w >> 2;          // 0..1  (M half)
    const int wc   = w & 3;           // 0..3  (N quarter, 48 cols)

    const int bid = blockIdx.x;       // 0..255 linear (no XCD remap: A-panel locality)
    const int mb  = (bid & 15) << 8;  // 16 M tiles of 256
    const int nb  = (bid >> 4) * 192; // 16 N tiles of 192

    // ---- staging geometry ----
    // A regions (128 rows, 2 loads/thread): row = w*16 + (lane>>3) (+8 for j=1)
    const int srowA = w * 16 + (lane >> 3);
    const int scolA = (((lane & 7) ^ (lane >> 3)) << 3);          // shorts
    const short* pA0 = g_X + (long)(mb       + srowA) * 1024 + scolA;
    const short* pA1 = g_X + (long)(mb + 128 + srowA) * 1024 + scolA;
    const int ldstA = w * 1024 + lane * 8;                        // shorts (+512 j=1)
    // B regions (64 rows, 1 load/thread): row = t>>3
    const int srowB = t >> 3;
    const int scolB = (((t & 7) ^ ((t >> 3) & 7)) << 3);          // shorts
    const short* pB0 = g_W + (long)(nb       + srowB) * 1024 + scolB;
    const short* pB1 = g_W + (long)(nb +  64 + srowB) * 1024 + scolB;
    const short* pB2 = g_W + (long)(nb + 128 + srowB) * 1024 + scolB;
    const int ldstB = t * 8;                                      // shorts

#define STAGE_A(buf_, reg_, gp_, kt_) do {                          \
        short* lp_ = &L[(buf_)][(reg_) + ldstA];                    \
        GLOAD_LDS((gp_) + (long)(kt_), lp_);                        \
        GLOAD_LDS((gp_) + 8192 + (long)(kt_), lp_ + 512);           \
    } while (0)
#define STAGE_B(buf_, reg_, gp_, kt_) do {                          \
        short* lp_ = &L[(buf_)][(reg_) + ldstB];                    \
        GLOAD_LDS((gp_) + (long)(kt_), lp_);                        \
    } while (0)
#define BARRIER() asm volatile("s_barrier" ::: "memory")

    // read-side swizzle (chunk ^= l15&7, in shorts)
    const int axs    = (l15 & 7) << 3;
    const int a_off0 = (qg << 3) ^ axs;
    const int a_off1 = (32 + (qg << 3)) ^ axs;
    // B read bases: wave cols wc*48 + ni*16; region/row within 3x64-row layout
    int breg[3], brr[3];
    #pragma unroll
    for (int ni = 0; ni < 3; ni++) {
        const int cb = wc * 48 + ni * 16;
        breg[ni] = RB0 + (cb >> 6) * 4096;   // region base (shorts)
        brr[ni]  = cb & 63;                  // 16-aligned -> row&7 == l15&7 holds
    }

    f32x4 acc[8][3] = {};

    // prologue: A0^0, A1^0, B^0 (7 loads), A0^1 (2) -> vmcnt(2): tile0 landed
    STAGE_A(0, RA0, pA0, 0);
    STAGE_A(0, RA1, pA1, 0);
    STAGE_B(0, RB0, pB0, 0);
    STAGE_B(0, RB1, pB1, 0);
    STAGE_B(0, RB2, pB2, 0);
    STAGE_A(1, RA0, pA0, 64);
    asm volatile("s_waitcnt vmcnt(2)" ::: "memory");
    BARRIER();

    for (int T = 0; T < QKV_NT; T++) {
        const int buf = T & 1;
        const short* Ah = L[buf] + (wr ? RA1 : RA0);
        short8 afr[4][2], bfr[3][2];

        // ---- p0: read A mi0-3 (8) + B ni0-1 (4); stage A1^{T+1}; MFMA mi0-3 x ni0-1
        #pragma unroll
        for (int mi = 0; mi < 4; mi++) {
            const int rb = (mi*16 + l15) * 64;
            afr[mi][0] = *(const short8*)(Ah + rb + a_off0);
            afr[mi][1] = *(const short8*)(Ah + rb + a_off1);
        }
        #pragma unroll
        for (int ni = 0; ni < 2; ni++) {
            const short* Bp = L[buf] + breg[ni] + (brr[ni] + l15) * 64;
            bfr[ni][0] = *(const short8*)(Bp + a_off0);
            bfr[ni][1] = *(const short8*)(Bp + a_off1);
        }
        if (T + 1 < QKV_NT) STAGE_A(buf ^ 1, RA1, pA1, (T+1)*64);
        BARRIER();
        __builtin_amdgcn_s_setprio(1);
        #pragma unroll
        for (int mi = 0; mi < 4; mi++)
            #pragma unroll
            for (int ni = 0; ni < 2; ni++) {
                acc[mi][ni] = __builtin_amdgcn_mfma_f32_16x16x32_bf16(afr[mi][0], bfr[ni][0], acc[mi][ni], 0, 0, 0);
                acc[mi][ni] = __builtin_amdgcn_mfma_f32_16x16x32_bf16(afr[mi][1], bfr[ni][1], acc[mi][ni], 0, 0, 0);
            }
        __builtin_amdgcn_s_setprio(0);
        BARRIER();

        // ---- p1: read B ni2 (2); stage B012^{T+1}; MFMA mi0-3 x ni2
        {
            const short* Bp = L[buf] + breg[2] + (brr[2] + l15) * 64;
            bfr[2][0] = *(const short8*)(Bp + a_off0);
            bfr[2][1] = *(const short8*)(Bp + a_off1);
        }
        if (T + 1 < QKV_NT) {
            STAGE_B(buf ^ 1, RB0, pB0, (T+1)*64);
            STAGE_B(buf ^ 1, RB1, pB1, (T+1)*64);
            STAGE_B(buf ^ 1, RB2, pB2, (T+1)*64);
        }
        BARRIER();
        __builtin_amdgcn_s_setprio(1);
        #pragma unroll
        for (int mi = 0; mi < 4; mi++) {
            acc[mi][2] = __builtin_amdgcn_mfma_f32_16x16x32_bf16(afr[mi][0], bfr[2][0], acc[mi][2], 0, 0, 0);
            acc[mi][2] = __builtin_amdgcn_mfma_f32_16x16x32_bf16(afr[mi][1], bfr[2][1], acc[mi][2], 0, 0, 0);
        }
        __builtin_amdgcn_s_setprio(0);
        BARRIER();

        // ---- p2: read A mi4-7 (8); MFMA mi4-7 x ni2
        #pragma unroll
        for (int mi = 0; mi < 4; mi++) {
            const int rb = ((mi + 4)*16 + l15) * 64;
            afr[mi][0] = *(const short8*)(Ah + rb + a_off0);
            afr[mi][1] = *(const short8*)(Ah + rb + a_off1);
        }
        BARRIER();
        __builtin_amdgcn_s_setprio(1);
        #pragma unroll
        for (int mi = 0; mi < 4; mi++) {
            acc[mi+4][2] = __builtin_amdgcn_mfma_f32_16x16x32_bf16(afr[mi][0], bfr[2][0], acc[mi+4][2], 0, 0, 0);
            acc[mi+4][2] = __builtin_amdgcn_mfma_f32_16x16x32_bf16(afr[mi][1], bfr[2][1], acc[mi+4][2], 0, 0, 0);
        }
        __builtin_amdgcn_s_setprio(0);
        BARRIER();

        // ---- p3: stage A0^{T+2} (after last A0 reads at p2); MFMA mi4-7 x ni0-1
        if (T + 2 < QKV_NT) STAGE_A(buf, RA0, pA0, (T+2)*64);
        __builtin_amdgcn_s_setprio(1);
        #pragma unroll
        for (int mi = 0; mi < 4; mi++)
            #pragma unroll
            for (int ni = 0; ni < 2; ni++) {
                acc[mi+4][ni] = __builtin_amdgcn_mfma_f32_16x16x32_bf16(afr[mi][0], bfr[ni][0], acc[mi+4][ni], 0, 0, 0);
                acc[mi+4][ni] = __builtin_amdgcn_mfma_f32_16x16x32_bf16(afr[mi][1], bfr[ni][1], acc[mi+4][ni], 0, 0, 0);
            }
        __builtin_amdgcn_s_setprio(0);
        if (T <= QKV_NT - 3)      asm volatile("s_waitcnt vmcnt(2)" ::: "memory");
        else if (T == QKV_NT - 2) asm volatile("s_waitcnt vmcnt(0)" ::: "memory");
        BARRIER();
    }

    // ---- epilogue: per-ni z (192-wide tiles straddle q|k|v at n=1024/2048) ----
    const int nbase = nb + wc * 48;
    short* Outp[3]; float bvv[3], scl[3]; int hh[3], db[3];
    #pragma unroll
    for (int ni = 0; ni < 3; ni++) {
        const int cc = nbase + ni * 16;       // 16-aligned -> z,h uniform over l15
        const int z = cc >> 10, cl = cc & 1023;
        Outp[ni] = (z == 0) ? g_Q : ((z == 1) ? g_K : g_V);
        scl[ni]  = (z == 0) ? 0.125f : 1.0f;
        hh[ni] = cl >> 6; db[ni] = cl & 63;
        bvv[ni] = bf2f(g_b[z * 1024 + cl + l15]);
    }
    const int rg = qg * 4;
    #pragma unroll
    for (int mi = 0; mi < 8; mi++) {
        #pragma unroll
        for (int r = 0; r < 4; r++) {
            const int row = mb + wr * 128 + mi * 16 + rg + r;
            const int bI = row >> 11, s = row & 2047;
            #pragma unroll
            for (int ni = 0; ni < 3; ni++)
                Outp[ni][(((long)(bI * NH + hh[ni]) * S_LEN) + s) * DK + db[ni] + l15] =
                    f2bf((acc[mi][ni][r] + bvv[ni]) * scl[ni]);
        }
    }
#undef STAGE_A
#undef STAGE_B
#undef BARRIER
}

// ------ Out-proj: 128x64 tiles, BK=32, dbuf prefetch, ONE barrier per K-step ------
__global__ __launch_bounds__(256) void o_gemm(float* __restrict__ Out)
{
    __shared__ __attribute__((aligned(16))) short As[2][128 * 32];
    __shared__ __attribute__((aligned(16))) short Bs[2][64 * 32];

    const short* __restrict__ A = g_AO;
    const short* __restrict__ W = g_W + 3L * W_ELEMS;

    const int t = threadIdx.x;
    const int lane = t & 63;
    const int wid  = t >> 6;
    const int wm = wid & 1, wn = wid >> 1;
    const int l15 = lane & 15;
    const int q8  = (lane >> 4) * 8;
    const int mb = blockIdx.x * 128;
    const int nb = blockIdx.y * 64;

    const long ga0 = (long)(mb + (t >> 2)) * 1024 + (t & 3) * 8;
    const long ga1 = (long)(mb + 64 + (t >> 2)) * 1024 + (t & 3) * 8;
    const long gb0 = (long)(nb + (t >> 2)) * 1024 + (t & 3) * 8;

    f32x4 acc[4][2] = {};

    GLOAD_LDS(A + ga0, As[0] + t * 8);
    GLOAD_LDS(A + ga1, As[0] + 2048 + t * 8);
    GLOAD_LDS(W + gb0, Bs[0] + t * 8);
    __syncthreads();

    for (int k0 = 0; k0 < 1024; k0 += 32) {
        const int cur = (k0 >> 5) & 1;
        if (k0 + 32 < 1024) {
            GLOAD_LDS(A + ga0 + k0 + 32, As[cur ^ 1] + t * 8);
            GLOAD_LDS(A + ga1 + k0 + 32, As[cur ^ 1] + 2048 + t * 8);
            GLOAD_LDS(W + gb0 + k0 + 32, Bs[cur ^ 1] + t * 8);
        }
        short8 a[4], b[2];
        #pragma unroll
        for (int mt = 0; mt < 4; mt++) a[mt] = *(const short8*)(As[cur] + (wm * 64 + mt * 16 + l15) * 32 + q8);
        #pragma unroll
        for (int nt = 0; nt < 2; nt++) b[nt] = *(const short8*)(Bs[cur] + (wn * 32 + nt * 16 + l15) * 32 + q8);
        #pragma unroll
        for (int mt = 0; mt < 4; mt++)
            #pragma unroll
            for (int nt = 0; nt < 2; nt++)
                acc[mt][nt] = __builtin_amdgcn_mfma_f32_16x16x32_bf16(a[mt], b[nt], acc[mt][nt], 0, 0, 0);
        __syncthreads();
    }

    const int rg = (lane >> 4) * 4;
    #pragma unroll
    for (int nt = 0; nt < 2; nt++) {
        const int col = nb + wn * 32 + nt * 16 + l15;
        const float bv_ = bf2f(g_b[3 * 1024 + col]);
        #pragma unroll
        for (int mt = 0; mt < 4; mt++) {
            #pragma unroll
            for (int r = 0; r < 4; r++) {
                const int row = mb + wm * 64 + mt * 16 + rg + r;
                Out[(long)row * 1024 + col] = acc[mt][nt][r] + bv_;
            }
        }
    }
}

// ------- Banded attention: 64 q/block, online softmax, K prefetch, XCD swizzle ------
#define VT_PAD 328   // 656 B = 164 dw; 164%32=4 -> 4-bank row skew (2-way, free)

__global__ __launch_bounds__(256) void attn_kernel()
{
    __shared__ __attribute__((aligned(16))) short Vt[64][VT_PAD];   // [dim][key-kb0]
    __shared__ __attribute__((aligned(16))) short Pl[4][16][72];    // per-wave P [row][key]

    const int bid  = blockIdx.x;
    const int head = bid & 31;          // b*16+h
    const int qt   = bid >> 5;          // 0..31
    const int h = head & 15, b = head >> 4;
    const int qbase = qt * 64;

    const int lane = threadIdx.x & 63;
    const int w    = threadIdx.x >> 6;
    const int l15  = lane & 15;
    const int qg   = lane >> 4;
    const int q8   = qg * 8;

    const long hoff = (long)(b * NH + h) * S_LEN * DK;
    const short* __restrict__ Qh = g_Q + hoff;
    const short* __restrict__ Kh = g_K + hoff;
    const short* __restrict__ Vh = g_V + hoff;

    const int lo  = qbase - (BANDW - 1);
    const int kc0 = (lo < 0 ? 0 : lo) >> 6;
    int hi = qbase + 64 + (BANDW - 1);
    if (hi > S_LEN) hi = S_LEN;
    const int kc1 = (hi + 63) >> 6;
    const int kb0 = kc0 * 64;
    const int n_keys = (kc1 - kc0) * 64;   // <= 320

    const short* qp = Qh + (long)(qbase + w * 16 + l15) * DK + q8;
    const short8 aq0 = *(const short8*)(qp);
    const short8 aq1 = *(const short8*)(qp + 32);

    const int npairs = n_keys >> 1;
    for (int u = threadIdx.x; u < npairs; u += 256) {
        const short* vp0 = Vh + (long)(kb0 + 2 * u) * DK;
        #pragma unroll
        for (int tq = 0; tq < 8; tq++) {
            const short8 v0 = *(const short8*)(vp0 + tq * 8);
            const short8 v1 = *(const short8*)(vp0 + DK + tq * 8);
            #pragma unroll
            for (int e = 0; e < 8; e++) {
                const int pk = (int)(unsigned short)v0[e] | ((int)(unsigned short)v1[e] << 16);
                *(int*)&Vt[tq * 8 + e][2 * u] = pk;
            }
        }
    }
    __syncthreads();

    short8 nk0[4], nk1[4];
    #pragma unroll
    for (int nt = 0; nt < 4; nt++) {
        const short* kp = Kh + (long)(kb0 + nt * 16 + l15) * DK + q8;
        nk0[nt] = *(const short8*)(kp);
        nk1[nt] = *(const short8*)(kp + 32);
    }

    f32x4 o[4] = {};
    float m_r[4], l_r[4];
    #pragma unroll
    for (int r = 0; r < 4; r++) { m_r[r] = -1e30f; l_r[r] = 0.f; }

    for (int kc = kc0; kc < kc1; kc++) {
        const int kb = kc * 64;
        const int kloc = kb - kb0;

        short8 bk0[4], bk1[4];
        #pragma unroll
        for (int nt = 0; nt < 4; nt++) { bk0[nt] = nk0[nt]; bk1[nt] = nk1[nt]; }
        if (kc + 1 < kc1) {
            const int kbn = kb + 64;
            #pragma unroll
            for (int nt = 0; nt < 4; nt++) {
                const short* kp = Kh + (long)(kbn + nt * 16 + l15) * DK + q8;
                nk0[nt] = *(const short8*)(kp);
                nk1[nt] = *(const short8*)(kp + 32);
            }
        }

        f32x4 sc[4];
        #pragma unroll
        for (int nt = 0; nt < 4; nt++) {
            f32x4 z = {};
            z = __builtin_amdgcn_mfma_f32_16x16x32_bf16(aq0, bk0[nt], z, 0, 0, 0);
            z = __builtin_amdgcn_mfma_f32_16x16x32_bf16(aq1, bk1[nt], z, 0, 0, 0);
            sc[nt] = z;
        }

        float pv[4][4];
        float mx[4] = {-1e30f, -1e30f, -1e30f, -1e30f};
        if (kb == qbase) {
            #pragma unroll
            for (int nt = 0; nt < 4; nt++)
                #pragma unroll
                for (int r = 0; r < 4; r++) {
                    pv[nt][r] = sc[nt][r];
                    mx[r] = fmaxf(mx[r], sc[nt][r]);
                }
        } else {
            #pragma unroll
            for (int nt = 0; nt < 4; nt++) {
                const int kg = kb + nt * 16 + l15;
                #pragma unroll
                for (int r = 0; r < 4; r++) {
                    const int qI = qbase + w * 16 + qg * 4 + r;
                    int dlt = qI - kg; if (dlt < 0) dlt = -dlt;
                    const float v = (dlt < BANDW) ? sc[nt][r] : -1e30f;
                    pv[nt][r] = v;
                    mx[r] = fmaxf(mx[r], v);
                }
            }
        }
        #pragma unroll
        for (int mk = 1; mk < 16; mk <<= 1)
            #pragma unroll
            for (int r = 0; r < 4; r++) mx[r] = fmaxf(mx[r], __shfl_xor(mx[r], mk, 64));

        float alpha[4], lnew[4];
        #pragma unroll
        for (int r = 0; r < 4; r++) {
            const float mn = fmaxf(m_r[r], mx[r]);
            alpha[r] = __builtin_exp2f((m_r[r] - mn) * 1.44269504f);
            m_r[r] = mn;
            lnew[r] = 0.f;
        }
        #pragma unroll
        for (int nt = 0; nt < 4; nt++)
            #pragma unroll
            for (int r = 0; r < 4; r++) {
                const float p = (pv[nt][r] > -0.5e30f)
                    ? __builtin_exp2f((pv[nt][r] - m_r[r]) * 1.44269504f) : 0.f;
                pv[nt][r] = p;
                lnew[r] += p;
            }
        #pragma unroll
        for (int mk = 1; mk < 16; mk <<= 1)
            #pragma unroll
            for (int r = 0; r < 4; r++) lnew[r] += __shfl_xor(lnew[r], mk, 64);
        #pragma unroll
        for (int r = 0; r < 4; r++) l_r[r] = l_r[r] * alpha[r] + lnew[r];
        #pragma unroll
        for (int nt2 = 0; nt2 < 4; nt2++)
            #pragma unroll
            for (int r = 0; r < 4; r++) o[nt2][r] *= alpha[r];

        #pragma unroll
        for (int nt = 0; nt < 4; nt++)
            #pragma unroll
            for (int r = 0; r < 4; r++)
                Pl[w][qg * 4 + r][nt * 16 + l15] = f2bf(pv[nt][r]);
        asm volatile("s_waitcnt lgkmcnt(0)" ::: "memory");
        const short8 ap0 = *(const short8*)(&Pl[w][l15][q8]);
        const short8 ap1 = *(const short8*)(&Pl[w][l15][32 + q8]);

        #pragma unroll
        for (int nt2 = 0; nt2 < 4; nt2++) {
            const short* vrow = &Vt[nt2 * 16 + l15][kloc];
            const short8 bv0 = *(const short8*)(vrow + q8);
            const short8 bv1 = *(const short8*)(vrow + 32 + q8);
            o[nt2] = __builtin_amdgcn_mfma_f32_16x16x32_bf16(ap0, bv0, o[nt2], 0, 0, 0);
            o[nt2] = __builtin_amdgcn_mfma_f32_16x16x32_bf16(ap1, bv1, o[nt2], 0, 0, 0);
        }
    }

    #pragma unroll
    for (int nt2 = 0; nt2 < 4; nt2++)
        #pragma unroll
        for (int r = 0; r < 4; r++) {
            const int qI = qbase + w * 16 + qg * 4 + r;
            const int d = nt2 * 16 + l15;
            g_AO[((long)b * S_LEN + qI) * 1024 + h * DK + d] = f2bf(o[nt2][r] / l_r[r]);
        }
}

extern "C" void kernel_launch(void* const* d_in, const int* in_sizes, int n_in,
                              void* d_out, int out_size, void* d_ws, size_t ws_size,
                              hipStream_t stream) {
    float* out = (float*)d_out;

    convert_all<<<(TOTC + 255) / 256, 256, 0, stream>>>(
        d_in[0], d_in[1], d_in[2], d_in[3], d_in[4], d_in[5], d_in[6], d_in[7], d_in[8]);
    qkv_gemm256<<<dim3(256), 512, 0, stream>>>();
    attn_kernel<<<dim3(2 * NH * (S_LEN / 64)), 256, 0, stream>>>();
    o_gemm<<<dim3(32, 16), 256, 0, stream>>>(out);
}

// Round 7
// 176.010 us; speedup vs baseline: 1.0254x; 1.0031x over previous
//
#include <hip/hip_runtime.h>
#include <hip/hip_bf16.h>

// B=2, S=2048, D=1024, H=16, DK=64, BAND=100. Inputs f32 (auto-detect; bf16 fallback).
// Output f32. R16 = exact R11 base (best known, 173.8us: qkv 256x256 8-phase linear-bid
// swizzled, attn, convert) + ONE change: o_gemm retiled 128x128, BK=64, grid 32x8=256
// (1/CU), 2-barrier structure with R11-derived 3-bit XOR LDS swizzle (BK=64 row stride
// is 128B -> 32-way conflict without it). 16 K-steps instead of 32 halves exposed
// latency events; A traffic halves (8 col-blocks vs 16).

typedef __attribute__((ext_vector_type(8))) short short8;
typedef __attribute__((ext_vector_type(4))) float f32x4;

#define S_LEN 2048
#define NH 16
#define DK 64
#define BANDW 100

#define X_ELEMS   (2 * S_LEN * 1024)
#define W_ELEMS   (1024 * 1024)
#define QKV_ELEMS (2 * NH * S_LEN * DK)
#define AO_ELEMS  (2 * S_LEN * 1024)

__device__ __attribute__((aligned(256))) short g_X[X_ELEMS];
__device__ __attribute__((aligned(256))) short g_W[4 * W_ELEMS];   // Wq|Wk|Wv|Wo
__device__ __attribute__((aligned(256))) short g_b[4 * 1024];      // bq|bk|bv|bo
__device__ __attribute__((aligned(256))) short g_Q[QKV_ELEMS];     // pre-scaled by 1/8
__device__ __attribute__((aligned(256))) short g_K[QKV_ELEMS];
__device__ __attribute__((aligned(256))) short g_V[QKV_ELEMS];     // row-major [B,H,S,DK]
__device__ __attribute__((aligned(256))) short g_AO[AO_ELEMS];

__device__ __forceinline__ float bf2f(short u) {
    unsigned x = ((unsigned)(unsigned short)u) << 16;
    return __builtin_bit_cast(float, x);
}
__device__ __forceinline__ short f2bf(float f) {
    unsigned x = __builtin_bit_cast(unsigned, f);
    unsigned r = (x + 0x7fffu + ((x >> 16) & 1u)) >> 16;
    return (short)r;
}

#define GLOAD_LDS(gp, lp) \
    __builtin_amdgcn_global_load_lds( \
        (const __attribute__((address_space(1))) void*)(gp), \
        (__attribute__((address_space(3))) void*)(lp), 16, 0, 0)

// ---------------- Fused detect + convert (R9 form) ----------------
#define XC   (X_ELEMS / 8)
#define WC   (W_ELEMS / 8)
#define BC   (1024 / 8)
#define TOTC (XC + 4 * WC + 4 * BC)

__global__ __launch_bounds__(256) void convert_all(
    const void* __restrict__ x,
    const void* __restrict__ w0, const void* __restrict__ b0,
    const void* __restrict__ w1, const void* __restrict__ b1,
    const void* __restrict__ w2, const void* __restrict__ b2,
    const void* __restrict__ w3, const void* __restrict__ b3)
{
    __shared__ int cnt[256];
    {
        const unsigned* xw = (const unsigned*)x;
        int local = 0;
        #pragma unroll
        for (int i = 0; i < 4; i++) {
            unsigned wv = xw[threadIdx.x * 4 + i];
            unsigned e = (wv >> 7) & 0xFF;
            if (e >= 100 && e <= 140) local++;
        }
        cnt[threadIdx.x] = local;
    }
    __syncthreads();
    for (int s = 128; s > 0; s >>= 1) {
        if (threadIdx.x < s) cnt[threadIdx.x] += cnt[threadIdx.x + s];
        __syncthreads();
    }
    const int is_bf16 = (cnt[0] > 512);

    long i = (long)blockIdx.x * 256 + threadIdx.x;
    if (i >= TOTC) return;

    const void* src; short* dst; long off;
    if (i < XC)                { src = x;  dst = g_X;              off = i; }
    else if ((i -= XC) < WC)   { src = w0; dst = g_W + 0L*W_ELEMS; off = i; }
    else if ((i -= WC) < WC)   { src = w1; dst = g_W + 1L*W_ELEMS; off = i; }
    else if ((i -= WC) < WC)   { src = w2; dst = g_W + 2L*W_ELEMS; off = i; }
    else if ((i -= WC) < WC)   { src = w3; dst = g_W + 3L*W_ELEMS; off = i; }
    else if ((i -= WC) < BC)   { src = b0; dst = g_b + 0*1024;     off = i; }
    else if ((i -= BC) < BC)   { src = b1; dst = g_b + 1*1024;     off = i; }
    else if ((i -= BC) < BC)   { src = b2; dst = g_b + 2*1024;     off = i; }
    else                       { src = b3; dst = g_b + 3*1024;     off = i - BC; }

    if (is_bf16) {
        ((short8*)dst)[off] = ((const short8*)src)[off];
    } else {
        const float* s = (const float*)src + off * 8;
        short8 o;
        #pragma unroll
        for (int e = 0; e < 8; e++) o[e] = f2bf(s[e]);
        ((short8*)dst)[off] = o;
    }
}

// ---------------- Fused QKV GEMM (R11, unchanged): 256x256, BK=64, 8-wave 8-phase ----
// M=4096, N=3072 (q|k|v), K=1024. LDS 2dbuf x {A,B} x 2 halves x [128][64] = 128 KiB.
// Swizzle: LDS byte b of a region holds global elem u = b ^ ((row(b)&7)<<4), row=b>>7.
// Stage side: linear dest, source chunk (lane&7)^(lane>>3). Read side: chunk ^ (l15&7).
// Stage schedule: p0:A1^{T+1} p1:B1^{T+1} p2:B0^{T+2} p3:A0^{T+2}; vmcnt(4)/tile.

#define LHALF 8192   // shorts per 16 KiB half-region

__global__ __launch_bounds__(512, 2) void qkv_gemm256()
{
    __shared__ __attribute__((aligned(16))) short L[8][LHALF]; // [buf*4 + mat*2 + half]

    const int t = threadIdx.x;
    const int lane = t & 63;
    const int w    = t >> 6;          // 0..7
    const int l15  = lane & 15;
    const int qg   = lane >> 4;       // 0..3
    const int wr   = w >> 2;          // 0..1  (M half owned by this wave)
    const int wc   = w & 3;           // 0..3  (N quarter)

    const int bid = blockIdx.x;       // 0..191 linear (A-panel L2 locality)
    const int mb  = (bid & 15) << 8;  // 16 M tiles
    const int nb  = (bid >> 4) << 8;  // 12 N tiles

    const int srow = w * 16 + (lane >> 3);                        // + j*8
    const int scol = (((lane & 7) ^ (lane >> 3)) << 3);           // shorts
    const short* pA0 = g_X + (long)(mb       + srow) * 1024 + scol;
    const short* pA1 = g_X + (long)(mb + 128 + srow) * 1024 + scol;
    const short* pB0 = g_W + (long)(nb       + srow) * 1024 + scol;
    const short* pB1 = g_W + (long)(nb + 128 + srow) * 1024 + scol;
    const int ldst = w * 1024 + lane * 8;                         // shorts; +512 for j=1

#define STAGE(reg_, gp_, kt_) do {                         \
        short* lp_ = &L[(reg_)][ldst];                     \
        GLOAD_LDS((gp_) + (long)(kt_), lp_);               \
        GLOAD_LDS((gp_) + 8192 + (long)(kt_), lp_ + 512);  \
    } while (0)

#define BARRIER() asm volatile("s_barrier" ::: "memory")

    const int axs    = (l15 & 7) << 3;            // XOR, in shorts (chunk ^ row&7)
    const int a_off0 = (qg << 3) ^ axs;           // kk = 0
    const int a_off1 = (32 + (qg << 3)) ^ axs;    // kk = 1
    const int brow   = (wc & 1) * 64;

    f32x4 acc[8][4] = {};

    STAGE(0*4 + 2 + 0, pB0, 0);
    STAGE(0*4 + 0 + 0, pA0, 0);
    STAGE(0*4 + 0 + 1, pA1, 0);
    STAGE(0*4 + 2 + 1, pB1, 0);
    STAGE(1*4 + 2 + 0, pB0, 64);
    STAGE(1*4 + 0 + 0, pA0, 64);
    asm volatile("s_waitcnt vmcnt(4)" ::: "memory");   // tile0's 4 halves landed
    BARRIER();

    for (int T = 0; T < 16; T++) {
        const int buf = T & 1;
        const short* Ah = L[buf*4 + wr];
        const short* Bh = L[buf*4 + 2 + (wc >> 1)];
        short8 afr[4][2], bfr[4][2];

        // p0: read A mi0-3 + B ni0-1; stage A1^{T+1}; MFMA Q(lo,lo)
        #pragma unroll
        for (int mi = 0; mi < 4; mi++) {
            const int rb = (mi*16 + l15) * 64;
            afr[mi][0] = *(const short8*)(Ah + rb + a_off0);
            afr[mi][1] = *(const short8*)(Ah + rb + a_off1);
        }
        #pragma unroll
        for (int ni = 0; ni < 2; ni++) {
            const int rb = (brow + ni*16 + l15) * 64;
            bfr[ni][0] = *(const short8*)(Bh + rb + a_off0);
            bfr[ni][1] = *(const short8*)(Bh + rb + a_off1);
        }
        if (T + 1 < 16) STAGE(((T+1)&1)*4 + 1, pA1, (T+1)*64);
        BARRIER();
        __builtin_amdgcn_s_setprio(1);
        #pragma unroll
        for (int mi = 0; mi < 4; mi++)
            #pragma unroll
            for (int ni = 0; ni < 2; ni++) {
                acc[mi][ni] = __builtin_amdgcn_mfma_f32_16x16x32_bf16(afr[mi][0], bfr[ni][0], acc[mi][ni], 0, 0, 0);
                acc[mi][ni] = __builtin_amdgcn_mfma_f32_16x16x32_bf16(afr[mi][1], bfr[ni][1], acc[mi][ni], 0, 0, 0);
            }
        __builtin_amdgcn_s_setprio(0);
        BARRIER();

        // p1: read B ni2-3; stage B1^{T+1}; MFMA Q(lo,hi)
        #pragma unroll
        for (int ni = 2; ni < 4; ni++) {
            const int rb = (brow + ni*16 + l15) * 64;
            bfr[ni][0] = *(const short8*)(Bh + rb + a_off0);
            bfr[ni][1] = *(const short8*)(Bh + rb + a_off1);
        }
        if (T + 1 < 16) STAGE(((T+1)&1)*4 + 2 + 1, pB1, (T+1)*64);
        BARRIER();
        __builtin_amdgcn_s_setprio(1);
        #pragma unroll
        for (int mi = 0; mi < 4; mi++)
            #pragma unroll
            for (int ni = 2; ni < 4; ni++) {
                acc[mi][ni] = __builtin_amdgcn_mfma_f32_16x16x32_bf16(afr[mi][0], bfr[ni][0], acc[mi][ni], 0, 0, 0);
                acc[mi][ni] = __builtin_amdgcn_mfma_f32_16x16x32_bf16(afr[mi][1], bfr[ni][1], acc[mi][ni], 0, 0, 0);
            }
        __builtin_amdgcn_s_setprio(0);
        BARRIER();

        // p2: read A mi4-7; stage B0^{T+2}; MFMA Q(hi,hi)
        #pragma unroll
        for (int mi = 0; mi < 4; mi++) {
            const int rb = ((mi + 4)*16 + l15) * 64;
            afr[mi][0] = *(const short8*)(Ah + rb + a_off0);
            afr[mi][1] = *(const short8*)(Ah + rb + a_off1);
        }
        if (T + 2 < 16) STAGE((T&1)*4 + 2 + 0, pB0, (T+2)*64);
        BARRIER();
        __builtin_amdgcn_s_setprio(1);
        #pragma unroll
        for (int mi = 0; mi < 4; mi++)
            #pragma unroll
            for (int ni = 2; ni < 4; ni++) {
                acc[mi+4][ni] = __builtin_amdgcn_mfma_f32_16x16x32_bf16(afr[mi][0], bfr[ni][0], acc[mi+4][ni], 0, 0, 0);
                acc[mi+4][ni] = __builtin_amdgcn_mfma_f32_16x16x32_bf16(afr[mi][1], bfr[ni][1], acc[mi+4][ni], 0, 0, 0);
            }
        __builtin_amdgcn_s_setprio(0);
        BARRIER();

        // p3: stage A0^{T+2}; MFMA Q(hi,lo); counted vmcnt; barrier
        if (T + 2 < 16) STAGE((T&1)*4 + 0, pA0, (T+2)*64);
        BARRIER();
        __builtin_amdgcn_s_setprio(1);
        #pragma unroll
        for (int mi = 0; mi < 4; mi++)
            #pragma unroll
            for (int ni = 0; ni < 2; ni++) {
                acc[mi+4][ni] = __builtin_amdgcn_mfma_f32_16x16x32_bf16(afr[mi][0], bfr[ni][0], acc[mi+4][ni], 0, 0, 0);
                acc[mi+4][ni] = __builtin_amdgcn_mfma_f32_16x16x32_bf16(afr[mi][1], bfr[ni][1], acc[mi+4][ni], 0, 0, 0);
            }
        __builtin_amdgcn_s_setprio(0);
        if (T <= 13)      asm volatile("s_waitcnt vmcnt(4)" ::: "memory");
        else if (T == 14) asm volatile("s_waitcnt vmcnt(0)" ::: "memory");
        BARRIER();
    }

    // epilogue: bias (+ Q scale); ni innermost so each 128B line completes
    const int nbase = nb + wc * 64;
    const int z = nbase >> 10;
    short* __restrict__ Out = (z == 0) ? g_Q : ((z == 1) ? g_K : g_V);
    const float scale = (z == 0) ? 0.125f : 1.0f;
    const int c0 = nbase & 1023;
    const int h = c0 >> 6;
    float bv4[4];
    #pragma unroll
    for (int ni = 0; ni < 4; ni++) bv4[ni] = bf2f(g_b[z * 1024 + c0 + ni * 16 + l15]);
    const int rg = qg * 4;
    #pragma unroll
    for (int mi = 0; mi < 8; mi++) {
        #pragma unroll
        for (int r = 0; r < 4; r++) {
            const int row = mb + wr * 128 + mi * 16 + rg + r;
            const int bI = row >> 11, s = row & 2047;
            short* op = Out + (((long)(bI * NH + h) * S_LEN) + s) * DK;
            #pragma unroll
            for (int ni = 0; ni < 4; ni++)
                op[ni * 16 + l15] = f2bf((acc[mi][ni][r] + bv4[ni]) * scale);
        }
    }
#undef STAGE
#undef BARRIER
}

// ------ Out-proj R16: 128x128 tile, BK=64, grid 32x8=256 (1/CU), 2-barrier ------
// LDS As/Bs each 128x64 sh (16KB), linear + 3-bit XOR swizzle (BK=64 => 128B row
// stride => 32-way conflict unswizzled). Stage instr j: thread t -> LDS sh
// j*2048+t*8, row=j*32+(t>>3), chunk=t&7; source chunk=(t&7)^(row&7).
// Read: row = w*64-part + mt*16 + l15; LDS chunk = (qg+4*kk)^(l15&7).
__global__ __launch_bounds__(256) void o_gemm(float* __restrict__ Out)
{
    __shared__ __attribute__((aligned(16))) short As[128 * 64];
    __shared__ __attribute__((aligned(16))) short Bs[128 * 64];

    const short* __restrict__ A = g_AO;
    const short* __restrict__ W = g_W + 3L * W_ELEMS;

    const int t = threadIdx.x;
    const int lane = t & 63;
    const int wid  = t >> 6;
    const int wm = wid & 1, wn = wid >> 1;
    const int l15 = lane & 15;
    const int qg  = (lane >> 4);
    const int mb = blockIdx.x * 128;
    const int nb = blockIdx.y * 128;

    // stage geometry (per instr j=0..3): row_j = j*32 + (t>>3), src chunk (t&7)^(row&7)
    const int srow = t >> 3;                               // + j*32
    const int scol = (((t & 7) ^ ((t >> 3) & 7)) << 3);    // shorts
    const short* pA = A + (long)(mb + srow) * 1024 + scol;
    const short* pB = W + (long)(nb + srow) * 1024 + scol;
    const int ldst = t * 8;                                // + j*2048

    // read-side swizzle
    const int axs    = (l15 & 7) << 3;
    const int a_off0 = (qg << 3) ^ axs;           // kk=0: chunks 0-3
    const int a_off1 = (32 + (qg << 3)) ^ axs;    // kk=1: chunks 4-7

    f32x4 acc[4][4] = {};

    for (int k0 = 0; k0 < 1024; k0 += 64) {
        __syncthreads();   // prior reads done before overwrite
        #pragma unroll
        for (int j = 0; j < 4; j++) {
            GLOAD_LDS(pA + (long)(j * 32) * 1024 + k0, As + j * 2048 + ldst);
            GLOAD_LDS(pB + (long)(j * 32) * 1024 + k0, Bs + j * 2048 + ldst);
        }
        __syncthreads();   // implicit vmcnt(0): tile landed

        short8 a[4][2], b[4][2];
        #pragma unroll
        for (int mt = 0; mt < 4; mt++) {
            const int rb = (wm * 64 + mt * 16 + l15) * 64;
            a[mt][0] = *(const short8*)(As + rb + a_off0);
            a[mt][1] = *(const short8*)(As + rb + a_off1);
        }
        #pragma unroll
        for (int nt = 0; nt < 4; nt++) {
            const int rb = (wn * 64 + nt * 16 + l15) * 64;
            b[nt][0] = *(const short8*)(Bs + rb + a_off0);
            b[nt][1] = *(const short8*)(Bs + rb + a_off1);
        }
        #pragma unroll
        for (int mt = 0; mt < 4; mt++)
            #pragma unroll
            for (int nt = 0; nt < 4; nt++) {
                acc[mt][nt] = __builtin_amdgcn_mfma_f32_16x16x32_bf16(a[mt][0], b[nt][0], acc[mt][nt], 0, 0, 0);
                acc[mt][nt] = __builtin_amdgcn_mfma_f32_16x16x32_bf16(a[mt][1], b[nt][1], acc[mt][nt], 0, 0, 0);
            }
    }

    const int rg = qg * 4;
    #pragma unroll
    for (int nt = 0; nt < 4; nt++) {
        const int col = nb + wn * 64 + nt * 16 + l15;
        const float bv_ = bf2f(g_b[3 * 1024 + col]);
        #pragma unroll
        for (int mt = 0; mt < 4; mt++) {
            #pragma unroll
            for (int r = 0; r < 4; r++) {
                const int row = mb + wm * 64 + mt * 16 + rg + r;
                Out[(long)row * 1024 + col] = acc[mt][nt][r] + bv_;
            }
        }
    }
}

// ------- Banded attention (R11, unchanged) ------
#define VT_PAD 328   // 656 B = 164 dw; 164%32=4 -> 4-bank row skew (2-way, free)

__global__ __launch_bounds__(256) void attn_kernel()
{
    __shared__ __attribute__((aligned(16))) short Vt[64][VT_PAD];   // [dim][key-kb0]
    __shared__ __attribute__((aligned(16))) short Pl[4][16][72];    // per-wave P [row][key]

    const int bid  = blockIdx.x;
    const int head = bid & 31;          // b*16+h
    const int qt   = bid >> 5;          // 0..31
    const int h = head & 15, b = head >> 4;
    const int qbase = qt * 64;

    const int lane = threadIdx.x & 63;
    const int w    = threadIdx.x >> 6;
    const int l15  = lane & 15;
    const int qg   = lane >> 4;
    const int q8   = qg * 8;

    const long hoff = (long)(b * NH + h) * S_LEN * DK;
    const short* __restrict__ Qh = g_Q + hoff;
    const short* __restrict__ Kh = g_K + hoff;
    const short* __restrict__ Vh = g_V + hoff;

    const int lo  = qbase - (BANDW - 1);
    const int kc0 = (lo < 0 ? 0 : lo) >> 6;
    int hi = qbase + 64 + (BANDW - 1);
    if (hi > S_LEN) hi = S_LEN;
    const int kc1 = (hi + 63) >> 6;
    const int kb0 = kc0 * 64;
    const int n_keys = (kc1 - kc0) * 64;   // <= 320

    const short* qp = Qh + (long)(qbase + w * 16 + l15) * DK + q8;
    const short8 aq0 = *(const short8*)(qp);
    const short8 aq1 = *(const short8*)(qp + 32);

    const int npairs = n_keys >> 1;
    for (int u = threadIdx.x; u < npairs; u += 256) {
        const short* vp0 = Vh + (long)(kb0 + 2 * u) * DK;
        #pragma unroll
        for (int tq = 0; tq < 8; tq++) {
            const short8 v0 = *(const short8*)(vp0 + tq * 8);
            const short8 v1 = *(const short8*)(vp0 + DK + tq * 8);
            #pragma unroll
            for (int e = 0; e < 8; e++) {
                const int pk = (int)(unsigned short)v0[e] | ((int)(unsigned short)v1[e] << 16);
                *(int*)&Vt[tq * 8 + e][2 * u] = pk;
            }
        }
    }
    __syncthreads();

    short8 nk0[4], nk1[4];
    #pragma unroll
    for (int nt = 0; nt < 4; nt++) {
        const short* kp = Kh + (long)(kb0 + nt * 16 + l15) * DK + q8;
        nk0[nt] = *(const short8*)(kp);
        nk1[nt] = *(const short8*)(kp + 32);
    }

    f32x4 o[4] = {};
    float m_r[4], l_r[4];
    #pragma unroll
    for (int r = 0; r < 4; r++) { m_r[r] = -1e30f; l_r[r] = 0.f; }

    for (int kc = kc0; kc < kc1; kc++) {
        const int kb = kc * 64;
        const int kloc = kb - kb0;

        short8 bk0[4], bk1[4];
        #pragma unroll
        for (int nt = 0; nt < 4; nt++) { bk0[nt] = nk0[nt]; bk1[nt] = nk1[nt]; }
        if (kc + 1 < kc1) {
            const int kbn = kb + 64;
            #pragma unroll
            for (int nt = 0; nt < 4; nt++) {
                const short* kp = Kh + (long)(kbn + nt * 16 + l15) * DK + q8;
                nk0[nt] = *(const short8*)(kp);
                nk1[nt] = *(const short8*)(kp + 32);
            }
        }

        f32x4 sc[4];
        #pragma unroll
        for (int nt = 0; nt < 4; nt++) {
            f32x4 z = {};
            z = __builtin_amdgcn_mfma_f32_16x16x32_bf16(aq0, bk0[nt], z, 0, 0, 0);
            z = __builtin_amdgcn_mfma_f32_16x16x32_bf16(aq1, bk1[nt], z, 0, 0, 0);
            sc[nt] = z;
        }

        float pv[4][4];
        float mx[4] = {-1e30f, -1e30f, -1e30f, -1e30f};
        if (kb == qbase) {
            #pragma unroll
            for (int nt = 0; nt < 4; nt++)
                #pragma unroll
                for (int r = 0; r < 4; r++) {
                    pv[nt][r] = sc[nt][r];
                    mx[r] = fmaxf(mx[r], sc[nt][r]);
                }
        } else {
            #pragma unroll
            for (int nt = 0; nt < 4; nt++) {
                const int kg = kb + nt * 16 + l15;
                #pragma unroll
                for (int r = 0; r < 4; r++) {
                    const int qI = qbase + w * 16 + qg * 4 + r;
                    int dlt = qI - kg; if (dlt < 0) dlt = -dlt;
                    const float v = (dlt < BANDW) ? sc[nt][r] : -1e30f;
                    pv[nt][r] = v;
                    mx[r] = fmaxf(mx[r], v);
                }
            }
        }
        #pragma unroll
        for (int mk = 1; mk < 16; mk <<= 1)
            #pragma unroll
            for (int r = 0; r < 4; r++) mx[r] = fmaxf(mx[r], __shfl_xor(mx[r], mk, 64));

        float alpha[4], lnew[4];
        #pragma unroll
        for (int r = 0; r < 4; r++) {
            const float mn = fmaxf(m_r[r], mx[r]);
            alpha[r] = __builtin_exp2f((m_r[r] - mn) * 1.44269504f);
            m_r[r] = mn;
            lnew[r] = 0.f;
        }
        #pragma unroll
        for (int nt = 0; nt < 4; nt++)
            #pragma unroll
            for (int r = 0; r < 4; r++) {
                const float p = (pv[nt][r] > -0.5e30f)
                    ? __builtin_exp2f((pv[nt][r] - m_r[r]) * 1.44269504f) : 0.f;
                pv[nt][r] = p;
                lnew[r] += p;
            }
        #pragma unroll
        for (int mk = 1; mk < 16; mk <<= 1)
            #pragma unroll
            for (int r = 0; r < 4; r++) lnew[r] += __shfl_xor(lnew[r], mk, 64);
        #pragma unroll
        for (int r = 0; r < 4; r++) l_r[r] = l_r[r] * alpha[r] + lnew[r];
        #pragma unroll
        for (int nt2 = 0; nt2 < 4; nt2++)
            #pragma unroll
            for (int r = 0; r < 4; r++) o[nt2][r] *= alpha[r];

        #pragma unroll
        for (int nt = 0; nt < 4; nt++)
            #pragma unroll
            for (int r = 0; r < 4; r++)
                Pl[w][qg * 4 + r][nt * 16 + l15] = f2bf(pv[nt][r]);
        asm volatile("s_waitcnt lgkmcnt(0)" ::: "memory");
        const short8 ap0 = *(const short8*)(&Pl[w][l15][q8]);
        const short8 ap1 = *(const short8*)(&Pl[w][l15][32 + q8]);

        #pragma unroll
        for (int nt2 = 0; nt2 < 4; nt2++) {
            const short* vrow = &Vt[nt2 * 16 + l15][kloc];
            const short8 bv0 = *(const short8*)(vrow + q8);
            const short8 bv1 = *(const short8*)(vrow + 32 + q8);
            o[nt2] = __builtin_amdgcn_mfma_f32_16x16x32_bf16(ap0, bv0, o[nt2], 0, 0, 0);
            o[nt2] = __builtin_amdgcn_mfma_f32_16x16x32_bf16(ap1, bv1, o[nt2], 0, 0, 0);
        }
    }

    #pragma unroll
    for (int nt2 = 0; nt2 < 4; nt2++)
        #pragma unroll
        for (int r = 0; r < 4; r++) {
            const int qI = qbase + w * 16 + qg * 4 + r;
            const int d = nt2 * 16 + l15;
            g_AO[((long)b * S_LEN + qI) * 1024 + h * DK + d] = f2bf(o[nt2][r] / l_r[r]);
        }
}

extern "C" void kernel_launch(void* const* d_in, const int* in_sizes, int n_in,
                              void* d_out, int out_size, void* d_ws, size_t ws_size,
                              hipStream_t stream) {
    float* out = (float*)d_out;

    convert_all<<<(TOTC + 255) / 256, 256, 0, stream>>>(
        d_in[0], d_in[1], d_in[2], d_in[3], d_in[4], d_in[5], d_in[6], d_in[7], d_in[8]);
    qkv_gemm256<<<dim3(192), 512, 0, stream>>>();
    attn_kernel<<<dim3(2 * NH * (S_LEN / 64)), 256, 0, stream>>>();
    o_gemm<<<dim3(32, 8), 256, 0, stream>>>(out);
}